// Round 6
// baseline (52.457 us; speedup 1.0000x reference)
//
#include <hip/hip_runtime.h>

// CFNet filter-adaptive convolution (customized FAC), fp32 — fully fused, 4 px/thread.
// feat_in: (8,3,512,512)  kernel: (8,100,256,256)  out: (8,3,256,256)
//
// Index mapping: for output (n,c2,h,w), tap t = 25*tb + 5*j + i:
//   (d,c) = table[tb][c2]
//   feat element = feat[n, c, clamp(2h+(w>>7)+i-2), clamp(4*(w&127)+d+j-2)]
//   kernel tap   = kernel[n, 10*i + 50*(a&1) + (a>>1), h, w],  a = 5*tb+j
//
// 4 pixels (w..w+3) per thread -> every kern tap is ONE float4 load
// (16 B/lane, 1 KB/wave-instruction). Round 6: kern loads are PLAIN float4
// (no nontemporal hint) — steady-state working set (~242 MB) fits the 256 MB
// Infinity Cache across graph replays; nt forbade that retention.

#define HH 256
#define WW 256
#define H2 512
#define W2 512
#define KPLANE (HH * WW)   // 65536
#define KP4 (KPLANE / 4)   // 16384 float4 per kernel plane

typedef float f32x4_t __attribute__((ext_vector_type(4)));

__global__ __launch_bounds__(256, 2) void fac_fused4(const float* __restrict__ feat,
                                                     const float* __restrict__ kern,
                                                     float* __restrict__ out) {
    int t  = blockIdx.x * 256 + threadIdx.x;   // 131072 threads total
    int qp = t & 63;             // pixel-quad index: w = 4*qp
    int h  = (t >> 6) & 255;
    int n  = t >> 14;
    int w  = qp << 2;

    int hi = (qp >> 5) & 1;      // = w>>7; row-half select from reshape wrap
    int xb = (qp & 31) << 4;     // = 4*(w&127): 0,16,...,496
    int y2 = 2 * h + hi;

    bool e0 = (qp & 31) == 0;    // left-edge lane class  (xb==0)
    bool e1 = (qp & 31) == 31;   // right-edge lane class (xb==496)
    int wbase = e0 ? 0 : (e1 ? 488 : (xb - 4));   // 24-float window base, 16B-aligned

    const f32x4_t* kp4 = (const f32x4_t*)(kern + (size_t)n * 100 * KPLANE +
                                          (size_t)h * WW + w);

    const int d_tab[4][3] = {{0,1,2},{0,1,3},{0,2,3},{1,2,3}};
    const int c_tab[4][3] = {{0,1,2},{1,2,0},{2,0,1},{0,1,2}};

    float acc[3][4] = {};

#pragma unroll 1
    for (int i = 0; i < 5; ++i) {
        int sy = min(max(y2 + i - 2, 0), H2 - 1);   // replicate pad in y

        // 24-float window per channel; 20 taps extracted w/ compile-time idx
        float fr[3][20];
#pragma unroll
        for (int c = 0; c < 3; ++c) {
            const float* rp = feat + ((size_t)(n * 3 + c) * H2 + sy) * W2 + wbase;
            float4 q0 = *(const float4*)(rp);
            float4 q1 = *(const float4*)(rp + 4);
            float4 q2 = *(const float4*)(rp + 8);
            float4 q3 = *(const float4*)(rp + 12);
            float4 q4 = *(const float4*)(rp + 16);
            float4 q5 = *(const float4*)(rp + 20);
            float win[24] = {q0.x, q0.y, q0.z, q0.w, q1.x, q1.y, q1.z, q1.w,
                             q2.x, q2.y, q2.z, q2.w, q3.x, q3.y, q3.z, q3.w,
                             q4.x, q4.y, q4.z, q4.w, q5.x, q5.y, q5.z, q5.w};
#pragma unroll
            for (int o = 0; o < 20; ++o) {
                // col = xb + o - 2 (clamped). win base: interior xb-4, e0 0, e1 488
                const int i_in = o + 2;
                const int i_e0 = (o - 2) < 0 ? 0 : (o - 2);
                const int i_e1 = (o + 6) > 23 ? 23 : (o + 6);
                fr[c][o] = e0 ? win[i_e0] : (e1 ? win[i_e1] : win[i_in]);
            }
        }

        const f32x4_t* kpi = kp4 + (size_t)i * 10 * KP4;
#pragma unroll
        for (int tb = 0; tb < 4; ++tb) {
#pragma unroll
            for (int j = 0; j < 5; ++j) {
                const int a5 = 5 * tb + j;                    // compile-time
                const int kc = (a5 & 1) * 50 + (a5 >> 1);     // +10*i via kpi
                f32x4_t kv = *(kpi + (size_t)kc * KP4);       // plain load (no nt)

                const int d0 = d_tab[tb][0], c0 = c_tab[tb][0];
                const int d1 = d_tab[tb][1], c1 = c_tab[tb][1];
                const int d2 = d_tab[tb][2], c2 = c_tab[tb][2];
#pragma unroll
                for (int p = 0; p < 4; ++p) {
                    acc[0][p] += kv[p] * fr[c0][d0 + j + 4 * p];
                    acc[1][p] += kv[p] * fr[c1][d1 + j + 4 * p];
                    acc[2][p] += kv[p] * fr[c2][d2 + j + 4 * p];
                }
            }
        }
    }

    float* op = out + (size_t)n * 3 * KPLANE + (size_t)h * WW + w;
#pragma unroll
    for (int c = 0; c < 3; ++c) {
        *(float4*)(op + (size_t)c * KPLANE) =
            make_float4(acc[c][0], acc[c][1], acc[c][2], acc[c][3]);
    }
}

extern "C" void kernel_launch(void* const* d_in, const int* in_sizes, int n_in,
                              void* d_out, int out_size, void* d_ws, size_t ws_size,
                              hipStream_t stream) {
    const float* feat = (const float*)d_in[0];   // 8*3*512*512
    const float* kern = (const float*)d_in[1];   // 8*100*256*256
    float* out = (float*)d_out;                  // 8*3*256*256

    // 131072 threads, 4 pixels each; 512 blocks
    fac_fused4<<<512, 256, 0, stream>>>(feat, kern, out);
}